// Round 3
// baseline (154.858 us; speedup 1.0000x reference)
//
#include <hip/hip_runtime.h>

// Problem constants (match reference)
#define BATCH  8192
#define KK     25
#define LL     25
#define BN_EPS 1e-5f
#define S1B    64          // stats1 blocks
#define LG     5           // l-values per mlp block (25/LG z-slices)
#define NLG    (LL / LG)

// Workspace layout (floats):
//   [0,    3200)  per-block partial sums: part[S1B][50]  (50 = sum[25], sumsq[25])
//   [3200, 3225)  scale[l]
//   [3232, 3257)  shift[l]
//   [4096, 4096+BATCH*LL)  xT[LL][BATCH]  (transposed x; only if ws big enough)
#define WS_PART   0
#define WS_SCALE  3200
#define WS_SHIFT  3232
#define WS_XT     4096

// ---------------------------------------------------------------------------
// stats1: grid-stride coalesced pass over ALL of x (each element exactly once).
//  - per-block partial sum / sumsq per column l (LDS fp32 atomics, l = e%25)
//  - optional transposed write xT[l][b] (makes mlp reads coalesced, no LDS)
//  - zeroes `out` (mlp accumulates with atomics; harness poisons out)
// R2 bug fixed: previous version read 12800 elems/block from 3200-stride
// bases -> 4x overlap + OOB. Now a single grid-stride loop, exact coverage.
// ---------------------------------------------------------------------------
__global__ __launch_bounds__(256) void stats1_kernel(
    const float* __restrict__ x,
    float* __restrict__ part,
    float* __restrict__ out,
    float* __restrict__ xT,
    int do_xT)
{
    __shared__ float bins[50];
    const int tid = threadIdx.x;
    const int blk = blockIdx.x;
    const int gid = blk * 256 + tid;
    const int nthreads = S1B * 256;

    if (tid < 50) bins[tid] = 0.f;
    __syncthreads();

    // zero the output accumulator (204800 floats over 16384 threads)
    for (int i = gid; i < BATCH * KK; i += nthreads)
        out[i] = 0.f;

    for (int e = gid; e < BATCH * LL; e += nthreads) {
        const float v = x[e];
        const int l = e % LL;
        const int b = e / LL;
        if (do_xT)
            xT[l * BATCH + b] = v;
        atomicAdd(&bins[l],      v);
        atomicAdd(&bins[LL + l], v * v);
    }
    __syncthreads();

    if (tid < 50) part[blk * 50 + tid] = bins[tid];
}

// ---------------------------------------------------------------------------
// stats2: reduce the 64 partials, emit scale/shift for xn = x*scale + shift
// ---------------------------------------------------------------------------
__global__ __launch_bounds__(64) void stats2_kernel(
    const float* __restrict__ part,
    const float* __restrict__ gamma,
    const float* __restrict__ bn_bias,
    float* __restrict__ ws)
{
    const int c = threadIdx.x;          // 0..63, columns 0..49 live
    float t = 0.f;
    if (c < 50)
        for (int b = 0; b < S1B; ++b)
            t += part[b * 50 + c];

    const int src = (c < 25) ? (c + 25) : c;
    const float s2 = __shfl(t, src);    // sumsq for column c (c<25)

    if (c < 25) {
        const float inv_b = 1.f / (float)BATCH;
        const float mean  = t * inv_b;
        const float var   = fmaf(s2, inv_b, -mean * mean);
        const float scale = rsqrtf(var + BN_EPS) * gamma[c];
        ws[WS_SCALE + c] = scale;
        ws[WS_SHIFT + c] = fmaf(-mean, scale, bn_bias[c]);
    }
}

// ---------------------------------------------------------------------------
// MLP body: one (k,l) tiny net on scalar xn. All weight addresses are
// wave-uniform -> s_load + v_fmac with SGPR sources.
// ---------------------------------------------------------------------------
__device__ __forceinline__ float mlp_eval(
    float xn, int kl,
    const float* __restrict__ W1, const float* __restrict__ b1,
    const float* __restrict__ W2, const float* __restrict__ b2,
    const float* __restrict__ W3, const float* __restrict__ b3,
    const float* __restrict__ W4, const float* __restrict__ b4)
{
    const float* w1  = W1 + kl * 8;
    const float* bb1 = b1 + kl * 8;
    float h1[8];
    #pragma unroll
    for (int h = 0; h < 8; ++h)
        h1[h] = fmaxf(fmaf(xn, w1[h], bb1[h]), 0.f);

    const float* w2  = W2 + kl * 64;
    const float* bb2 = b2 + kl * 8;
    float h2[8];
    #pragma unroll
    for (int i = 0; i < 8; ++i) {
        float t = bb2[i];
        #pragma unroll
        for (int h = 0; h < 8; ++h)
            t = fmaf(h1[h], w2[i * 8 + h], t);
        h2[i] = fmaxf(t, 0.f);
    }

    const float* w3  = W3 + kl * 48;
    const float* bb3 = b3 + kl * 6;
    float h3[6];
    #pragma unroll
    for (int j = 0; j < 6; ++j) {
        float t = bb3[j];
        #pragma unroll
        for (int i = 0; i < 8; ++i)
            t = fmaf(h2[i], w3[j * 8 + i], t);
        h3[j] = fmaxf(t, 0.f);
    }

    const float* w4 = W4 + kl * 6;
    float f = b4[kl];
    #pragma unroll
    for (int j = 0; j < 6; ++j)
        f = fmaf(h3[j], w4[j], f);
    return f;
}

// ---------------------------------------------------------------------------
// mlp (xT path): thread = (b,k), block handles LG l-values (blockIdx.z).
// No LDS; xn reads from transposed x are fully coalesced and L2-resident.
// grid = 32 x 25 x 5 = 4000 blocks -> full occupancy (vs R1's 3.1 waves/SIMD)
// ---------------------------------------------------------------------------
__global__ __launch_bounds__(256, 8) void mlp_xt_kernel(
    const float* __restrict__ xT,
    const float* __restrict__ W1, const float* __restrict__ b1,
    const float* __restrict__ W2, const float* __restrict__ b2,
    const float* __restrict__ W3, const float* __restrict__ b3,
    const float* __restrict__ W4, const float* __restrict__ b4,
    const float* __restrict__ alpha, const float* __restrict__ beta,
    const float* __restrict__ ws,
    float* __restrict__ out)
{
    const int tid = threadIdx.x;
    const int k   = blockIdx.y;
    const int b   = blockIdx.x * 256 + tid;
    const int l0  = blockIdx.z * LG;

    float acc = (blockIdx.z == 0) ? beta[k] : 0.f;

    for (int j = 0; j < LG; ++j) {
        const int l  = l0 + j;
        const int kl = k * LL + l;
        const float xn = fmaf(xT[l * BATCH + b], ws[WS_SCALE + l], ws[WS_SHIFT + l]);
        const float f  = mlp_eval(xn, kl, W1, b1, W2, b2, W3, b3, W4, b4);
        acc = fmaf(alpha[l * KK + k], f, acc);
    }

    unsafeAtomicAdd(&out[(size_t)b * KK + k], acc);
}

// ---------------------------------------------------------------------------
// mlp (LDS fallback if ws too small for xT): stage x chunk, same z-split.
// ---------------------------------------------------------------------------
__global__ __launch_bounds__(256) void mlp_lds_kernel(
    const float* __restrict__ x,
    const float* __restrict__ W1, const float* __restrict__ b1,
    const float* __restrict__ W2, const float* __restrict__ b2,
    const float* __restrict__ W3, const float* __restrict__ b3,
    const float* __restrict__ W4, const float* __restrict__ b4,
    const float* __restrict__ alpha, const float* __restrict__ beta,
    const float* __restrict__ ws,
    float* __restrict__ out)
{
    __shared__ float xs[256 * LL];
    const int tid = threadIdx.x;
    const int k   = blockIdx.y;
    const int b0  = blockIdx.x * 256;
    const int l0  = blockIdx.z * LG;

    const float* xsrc = x + (size_t)b0 * LL;
    #pragma unroll
    for (int i = 0; i < LL; ++i)
        xs[i * 256 + tid] = xsrc[i * 256 + tid];
    __syncthreads();

    float acc = (blockIdx.z == 0) ? beta[k] : 0.f;

    for (int j = 0; j < LG; ++j) {
        const int l  = l0 + j;
        const int kl = k * LL + l;
        const float xn = fmaf(xs[tid * LL + l], ws[WS_SCALE + l], ws[WS_SHIFT + l]);
        const float f  = mlp_eval(xn, kl, W1, b1, W2, b2, W3, b3, W4, b4);
        acc = fmaf(alpha[l * KK + k], f, acc);
    }

    unsafeAtomicAdd(&out[(size_t)(b0 + tid) * KK + k], acc);
}

extern "C" void kernel_launch(void* const* d_in, const int* in_sizes, int n_in,
                              void* d_out, int out_size, void* d_ws, size_t ws_size,
                              hipStream_t stream) {
    const float* x       = (const float*)d_in[0];
    const float* gamma   = (const float*)d_in[1];
    const float* bn_bias = (const float*)d_in[2];
    const float* W1      = (const float*)d_in[3];
    const float* b1      = (const float*)d_in[4];
    const float* W2      = (const float*)d_in[5];
    const float* b2      = (const float*)d_in[6];
    const float* W3      = (const float*)d_in[7];
    const float* b3      = (const float*)d_in[8];
    const float* W4      = (const float*)d_in[9];
    const float* b4      = (const float*)d_in[10];
    const float* alpha   = (const float*)d_in[11];
    const float* beta    = (const float*)d_in[12];

    float* out = (float*)d_out;
    float* ws  = (float*)d_ws;

    const size_t need = (size_t)(WS_XT + BATCH * LL) * sizeof(float);
    const int big = (ws_size >= need) ? 1 : 0;
    float* xT = ws + WS_XT;

    stats1_kernel<<<dim3(S1B), dim3(256), 0, stream>>>(x, ws + WS_PART, out, xT, big);
    stats2_kernel<<<dim3(1), dim3(64), 0, stream>>>(ws + WS_PART, gamma, bn_bias, ws);

    dim3 grid(BATCH / 256, KK, NLG);
    if (big) {
        mlp_xt_kernel<<<grid, dim3(256), 0, stream>>>(
            xT, W1, b1, W2, b2, W3, b3, W4, b4, alpha, beta, ws, out);
    } else {
        mlp_lds_kernel<<<grid, dim3(256), 0, stream>>>(
            x, W1, b1, W2, b2, W3, b3, W4, b4, alpha, beta, ws, out);
    }
}

// Round 4
// 118.360 us; speedup vs baseline: 1.3084x; 1.3084x over previous
//
#include <hip/hip_runtime.h>

// Problem constants (match reference)
#define BATCH  8192
#define KK     25
#define LL     25
#define BN_EPS 1e-5f
#define PREPB  32              // prep blocks = BATCH/256
#define LG     5               // l-values per eval block
#define NLG    (LL / LG)

// Workspace layout (float offsets):
#define WS_PART   0                         // [PREPB][50] partial sums
#define WS_SCALE  1600
#define WS_SHIFT  1632
#define WS_XT     2048                      // [LL][BATCH] transposed x
#define WS_FP     (WS_XT + LL * BATCH)      // [NLG][KK][BATCH] partial outputs
#define WS_END    (WS_FP + NLG * KK * BATCH)

// ---------------------------------------------------------------------------
// prep: coalesced read of x chunk -> LDS; coalesced transposed write to xT;
// per-column partial sum/sumsq (no atomics). 32 blocks x 256 rows.
// ---------------------------------------------------------------------------
__global__ __launch_bounds__(256) void prep_kernel(
    const float* __restrict__ x,
    float* __restrict__ xT,
    float* __restrict__ part)
{
    __shared__ float xs[256 * LL];          // 25.6 KB
    const int tid = threadIdx.x;
    const int b0  = blockIdx.x * 256;

    // stage 256 rows x 25 cols, fully coalesced
    const float* src = x + (size_t)b0 * LL;
    #pragma unroll
    for (int i = 0; i < LL; ++i)
        xs[i * 256 + tid] = src[i * 256 + tid];
    __syncthreads();

    // transposed write: for each l, lanes write consecutive b -> coalesced.
    // LDS read xs[tid*25+l]: stride 25, gcd(25,32)=1 -> 2 lanes/bank (free).
    #pragma unroll
    for (int l = 0; l < LL; ++l)
        xT[l * BATCH + b0 + tid] = xs[tid * LL + l];

    // column partial sums: threads 0..199 -> (group g=tid/25, col l=tid%25),
    // each sums 32 rows of column l.
    float s = 0.f, s2 = 0.f;
    if (tid < 200) {
        const int l = tid % LL;
        const int g = tid / LL;
        #pragma unroll
        for (int r = 0; r < 32; ++r) {
            const float v = xs[(g * 32 + r) * LL + l];
            s += v;
            s2 = fmaf(v, v, s2);
        }
    }
    __syncthreads();                        // all xs reads done
    if (tid < 200) { xs[tid] = s; xs[200 + tid] = s2; }
    __syncthreads();

    if (tid < 50) {
        const int c = tid;
        float t = 0.f;
        if (c < LL) {
            #pragma unroll
            for (int g = 0; g < 8; ++g) t += xs[g * LL + c];
        } else {
            #pragma unroll
            for (int g = 0; g < 8; ++g) t += xs[200 + g * LL + (c - LL)];
        }
        part[blockIdx.x * 50 + c] = t;
    }
}

// ---------------------------------------------------------------------------
// stats2: reduce PREPB partials -> scale/shift for xn = x*scale + shift
// ---------------------------------------------------------------------------
__global__ __launch_bounds__(64) void stats2_kernel(
    const float* __restrict__ part,
    const float* __restrict__ gamma,
    const float* __restrict__ bn_bias,
    float* __restrict__ ws)
{
    const int c = threadIdx.x;              // 0..63, columns 0..49 live
    float t = 0.f;
    if (c < 50)
        for (int b = 0; b < PREPB; ++b)
            t += part[b * 50 + c];

    const int src = (c < LL) ? (c + LL) : c;
    const float s2 = __shfl(t, src);        // sumsq for column c (c<25)

    if (c < LL) {
        const float inv_b = 1.f / (float)BATCH;
        const float mean  = t * inv_b;
        const float var   = fmaf(s2, inv_b, -mean * mean);
        const float scale = rsqrtf(var + BN_EPS) * gamma[c];
        ws[WS_SCALE + c] = scale;
        ws[WS_SHIFT + c] = fmaf(-mean, scale, bn_bias[c]);
    }
}

// ---------------------------------------------------------------------------
// MLP body: one (k,l) tiny net on scalar xn. All weight addresses are
// wave-uniform -> s_load + v_fmac with SGPR sources (verified R1: SGPR=112).
// ---------------------------------------------------------------------------
__device__ __forceinline__ float mlp_eval(
    float xn, int kl,
    const float* __restrict__ W1, const float* __restrict__ b1,
    const float* __restrict__ W2, const float* __restrict__ b2,
    const float* __restrict__ W3, const float* __restrict__ b3,
    const float* __restrict__ W4, const float* __restrict__ b4)
{
    const float* w1  = W1 + kl * 8;
    const float* bb1 = b1 + kl * 8;
    float h1[8];
    #pragma unroll
    for (int h = 0; h < 8; ++h)
        h1[h] = fmaxf(fmaf(xn, w1[h], bb1[h]), 0.f);

    const float* w2  = W2 + kl * 64;
    const float* bb2 = b2 + kl * 8;
    float h2[8];
    #pragma unroll
    for (int i = 0; i < 8; ++i) {
        float t = bb2[i];
        #pragma unroll
        for (int h = 0; h < 8; ++h)
            t = fmaf(h1[h], w2[i * 8 + h], t);
        h2[i] = fmaxf(t, 0.f);
    }

    const float* w3  = W3 + kl * 48;
    const float* bb3 = b3 + kl * 6;
    float h3[6];
    #pragma unroll
    for (int j = 0; j < 6; ++j) {
        float t = bb3[j];
        #pragma unroll
        for (int i = 0; i < 8; ++i)
            t = fmaf(h2[i], w3[j * 8 + i], t);
        h3[j] = fmaxf(t, 0.f);
    }

    const float* w4 = W4 + kl * 6;
    float f = b4[kl];
    #pragma unroll
    for (int j = 0; j < 6; ++j)
        f = fmaf(h3[j], w4[j], f);
    return f;
}

// ---------------------------------------------------------------------------
// eval: block (bchunk, k, g) handles LG l-values; sums alpha-weighted MLP
// outputs in-register; ONE coalesced streaming store to a disjoint fp slot.
// NO atomics (R3's 32 MB WRITE_SIZE / coherence-point stall eliminated).
// ---------------------------------------------------------------------------
__global__ __launch_bounds__(256) void eval_kernel(
    const float* __restrict__ xT,
    const float* __restrict__ W1, const float* __restrict__ b1,
    const float* __restrict__ W2, const float* __restrict__ b2,
    const float* __restrict__ W3, const float* __restrict__ b3,
    const float* __restrict__ W4, const float* __restrict__ b4,
    const float* __restrict__ alpha,
    const float* __restrict__ ws,
    float* __restrict__ fp)
{
    const int tid = threadIdx.x;
    const int k   = blockIdx.y;
    const int g   = blockIdx.z;
    const int b   = blockIdx.x * 256 + tid;
    const int l0  = g * LG;

    float acc = 0.f;
    for (int j = 0; j < LG; ++j) {
        const int l  = l0 + j;
        const int kl = k * LL + l;
        const float xn = fmaf(xT[l * BATCH + b], ws[WS_SCALE + l], ws[WS_SHIFT + l]);
        const float f  = mlp_eval(xn, kl, W1, b1, W2, b2, W3, b3, W4, b4);
        acc = fmaf(alpha[l * KK + k], f, acc);
    }
    fp[(g * KK + k) * BATCH + b] = acc;
}

// ---------------------------------------------------------------------------
// reduce: out[b][k] = beta[k] + sum_g fp[g][k][b]; coalesced loads, one store.
// ---------------------------------------------------------------------------
__global__ __launch_bounds__(256) void reduce_kernel(
    const float* __restrict__ fp,
    const float* __restrict__ beta,
    float* __restrict__ out)
{
    const int tid = threadIdx.x;
    const int k   = blockIdx.y;
    const int b   = blockIdx.x * 256 + tid;

    float acc = beta[k];
    #pragma unroll
    for (int g = 0; g < NLG; ++g)
        acc += fp[(g * KK + k) * BATCH + b];
    out[(size_t)b * KK + k] = acc;
}

// ---------------------------------------------------------------------------
// medium fallback (ws fits xT but not fp): full 25-l loop, direct store.
// ---------------------------------------------------------------------------
__global__ __launch_bounds__(256) void direct_xt_kernel(
    const float* __restrict__ xT,
    const float* __restrict__ W1, const float* __restrict__ b1,
    const float* __restrict__ W2, const float* __restrict__ b2,
    const float* __restrict__ W3, const float* __restrict__ b3,
    const float* __restrict__ W4, const float* __restrict__ b4,
    const float* __restrict__ alpha, const float* __restrict__ beta,
    const float* __restrict__ ws,
    float* __restrict__ out)
{
    const int tid = threadIdx.x;
    const int k   = blockIdx.y;
    const int b   = blockIdx.x * 256 + tid;

    float acc = beta[k];
    for (int l = 0; l < LL; ++l) {
        const int kl = k * LL + l;
        const float xn = fmaf(xT[l * BATCH + b], ws[WS_SCALE + l], ws[WS_SHIFT + l]);
        const float f  = mlp_eval(xn, kl, W1, b1, W2, b2, W3, b3, W4, b4);
        acc = fmaf(alpha[l * KK + k], f, acc);
    }
    out[(size_t)b * KK + k] = acc;
}

// ---------------------------------------------------------------------------
// tiny-ws fallback: R1 stats (column-strided) + LDS-staged direct mlp.
// ---------------------------------------------------------------------------
__global__ __launch_bounds__(256) void stats_small_kernel(
    const float* __restrict__ x,
    const float* __restrict__ gamma,
    const float* __restrict__ bn_bias,
    float* __restrict__ ws)
{
    const int l   = blockIdx.x;
    const int tid = threadIdx.x;

    float s = 0.f, s2 = 0.f;
    for (int b = tid; b < BATCH; b += 256) {
        float v = x[b * LL + l];
        s  += v;
        s2  = fmaf(v, v, s2);
    }
    for (int off = 32; off > 0; off >>= 1) {
        s  += __shfl_down(s,  off);
        s2 += __shfl_down(s2, off);
    }
    __shared__ float red[8];
    const int wave = tid >> 6;
    if ((tid & 63) == 0) { red[wave] = s; red[4 + wave] = s2; }
    __syncthreads();
    if (tid == 0) {
        s  = red[0] + red[1] + red[2] + red[3];
        s2 = red[4] + red[5] + red[6] + red[7];
        const float inv_b = 1.f / (float)BATCH;
        float mean = s * inv_b;
        float var  = fmaf(s2, inv_b, -mean * mean);
        float scale = rsqrtf(var + BN_EPS) * gamma[l];
        ws[WS_SCALE + l] = scale;
        ws[WS_SHIFT + l] = fmaf(-mean, scale, bn_bias[l]);
    }
}

__global__ __launch_bounds__(256) void mlp_lds_direct_kernel(
    const float* __restrict__ x,
    const float* __restrict__ W1, const float* __restrict__ b1,
    const float* __restrict__ W2, const float* __restrict__ b2,
    const float* __restrict__ W3, const float* __restrict__ b3,
    const float* __restrict__ W4, const float* __restrict__ b4,
    const float* __restrict__ alpha, const float* __restrict__ beta,
    const float* __restrict__ ws,
    float* __restrict__ out)
{
    __shared__ float xs[256 * LL];
    const int tid = threadIdx.x;
    const int k   = blockIdx.y;
    const int b0  = blockIdx.x * 256;

    const float* xsrc = x + (size_t)b0 * LL;
    #pragma unroll
    for (int i = 0; i < LL; ++i)
        xs[i * 256 + tid] = xsrc[i * 256 + tid];
    __syncthreads();

    float acc = beta[k];
    for (int l = 0; l < LL; ++l) {
        const int kl = k * LL + l;
        const float xn = fmaf(xs[tid * LL + l], ws[WS_SCALE + l], ws[WS_SHIFT + l]);
        const float f  = mlp_eval(xn, kl, W1, b1, W2, b2, W3, b3, W4, b4);
        acc = fmaf(alpha[l * KK + k], f, acc);
    }
    out[(size_t)(b0 + tid) * KK + k] = acc;
}

extern "C" void kernel_launch(void* const* d_in, const int* in_sizes, int n_in,
                              void* d_out, int out_size, void* d_ws, size_t ws_size,
                              hipStream_t stream) {
    const float* x       = (const float*)d_in[0];
    const float* gamma   = (const float*)d_in[1];
    const float* bn_bias = (const float*)d_in[2];
    const float* W1      = (const float*)d_in[3];
    const float* b1      = (const float*)d_in[4];
    const float* W2      = (const float*)d_in[5];
    const float* b2      = (const float*)d_in[6];
    const float* W3      = (const float*)d_in[7];
    const float* b3      = (const float*)d_in[8];
    const float* W4      = (const float*)d_in[9];
    const float* b4      = (const float*)d_in[10];
    const float* alpha   = (const float*)d_in[11];
    const float* beta    = (const float*)d_in[12];

    float* out = (float*)d_out;
    float* ws  = (float*)d_ws;
    float* xT  = ws + WS_XT;
    float* fp  = ws + WS_FP;

    const bool fast = ws_size >= (size_t)WS_END * sizeof(float);
    const bool med  = ws_size >= (size_t)WS_FP  * sizeof(float);

    if (fast || med) {
        prep_kernel<<<dim3(PREPB), dim3(256), 0, stream>>>(x, xT, ws + WS_PART);
        stats2_kernel<<<dim3(1), dim3(64), 0, stream>>>(ws + WS_PART, gamma, bn_bias, ws);
        if (fast) {
            eval_kernel<<<dim3(BATCH / 256, KK, NLG), dim3(256), 0, stream>>>(
                xT, W1, b1, W2, b2, W3, b3, W4, b4, alpha, ws, fp);
            reduce_kernel<<<dim3(BATCH / 256, KK), dim3(256), 0, stream>>>(fp, beta, out);
        } else {
            direct_xt_kernel<<<dim3(BATCH / 256, KK), dim3(256), 0, stream>>>(
                xT, W1, b1, W2, b2, W3, b3, W4, b4, alpha, beta, ws, out);
        }
    } else {
        stats_small_kernel<<<dim3(LL), dim3(256), 0, stream>>>(x, gamma, bn_bias, ws);
        mlp_lds_direct_kernel<<<dim3(BATCH / 256, KK), dim3(256), 0, stream>>>(
            x, W1, b1, W2, b2, W3, b3, W4, b4, alpha, beta, ws, out);
    }
}

// Round 5
// 113.238 us; speedup vs baseline: 1.3675x; 1.0452x over previous
//
#include <hip/hip_runtime.h>

// Problem constants (match reference)
#define BATCH  8192
#define KK     25
#define LL     25
#define BN_EPS 1e-5f
#define PREPB  32              // prep blocks = BATCH/256
#define LG     5               // l-values per eval block
#define NLG    (LL / LG)
#define VB     4               // batch elements per thread in eval (reg blocking)

// Workspace layout (float offsets):
#define WS_PART   0                         // [PREPB][50] partial sums
#define WS_SCALE  1600
#define WS_SHIFT  1632
#define WS_XT     2048                      // [LL][BATCH] transposed x
#define WS_FP     (WS_XT + LL * BATCH)      // [NLG][KK][BATCH] partial outputs
#define WS_END    (WS_FP + NLG * KK * BATCH)

// ---------------------------------------------------------------------------
// prep: coalesced read of x chunk -> LDS; coalesced transposed write to xT;
// per-column partial sum/sumsq (no atomics). 32 blocks x 256 rows.
// ---------------------------------------------------------------------------
__global__ __launch_bounds__(256) void prep_kernel(
    const float* __restrict__ x,
    float* __restrict__ xT,
    float* __restrict__ part)
{
    __shared__ float xs[256 * LL];          // 25.6 KB
    const int tid = threadIdx.x;
    const int b0  = blockIdx.x * 256;

    const float* src = x + (size_t)b0 * LL;
    #pragma unroll
    for (int i = 0; i < LL; ++i)
        xs[i * 256 + tid] = src[i * 256 + tid];
    __syncthreads();

    // transposed write: lanes write consecutive b -> coalesced.
    // LDS read stride 25 dwords, gcd(25,32)=1 -> 2 lanes/bank (free).
    #pragma unroll
    for (int l = 0; l < LL; ++l)
        xT[l * BATCH + b0 + tid] = xs[tid * LL + l];

    float s = 0.f, s2 = 0.f;
    if (tid < 200) {
        const int l = tid % LL;
        const int g = tid / LL;
        #pragma unroll
        for (int r = 0; r < 32; ++r) {
            const float v = xs[(g * 32 + r) * LL + l];
            s += v;
            s2 = fmaf(v, v, s2);
        }
    }
    __syncthreads();
    if (tid < 200) { xs[tid] = s; xs[200 + tid] = s2; }
    __syncthreads();

    if (tid < 50) {
        const int c = tid;
        float t = 0.f;
        if (c < LL) {
            #pragma unroll
            for (int g = 0; g < 8; ++g) t += xs[g * LL + c];
        } else {
            #pragma unroll
            for (int g = 0; g < 8; ++g) t += xs[200 + g * LL + (c - LL)];
        }
        part[blockIdx.x * 50 + c] = t;
    }
}

// ---------------------------------------------------------------------------
// stats2: reduce PREPB partials -> scale/shift for xn = x*scale + shift
// ---------------------------------------------------------------------------
__global__ __launch_bounds__(64) void stats2_kernel(
    const float* __restrict__ part,
    const float* __restrict__ gamma,
    const float* __restrict__ bn_bias,
    float* __restrict__ ws)
{
    const int c = threadIdx.x;
    float t = 0.f;
    if (c < 50)
        for (int b = 0; b < PREPB; ++b)
            t += part[b * 50 + c];

    const int src = (c < LL) ? (c + LL) : c;
    const float s2 = __shfl(t, src);

    if (c < LL) {
        const float inv_b = 1.f / (float)BATCH;
        const float mean  = t * inv_b;
        const float var   = fmaf(s2, inv_b, -mean * mean);
        const float scale = rsqrtf(var + BN_EPS) * gamma[c];
        ws[WS_SCALE + c] = scale;
        ws[WS_SHIFT + c] = fmaf(-mean, scale, bn_bias[c]);
    }
}

// ---------------------------------------------------------------------------
// eval: block (bchunk, k, g). Each thread handles VB=4 consecutive batch
// elements, so every (wave-uniform, s_load'ed) weight dword feeds 4x the
// VALU work -> amortizes the SGPR-reload latency that capped R3/R4 at
// VALUBusy ~31%. float4 xT loads, float4 fp stores, no atomics.
// ---------------------------------------------------------------------------
__global__ __launch_bounds__(256) void eval_kernel(
    const float* __restrict__ xT,
    const float* __restrict__ W1, const float* __restrict__ b1,
    const float* __restrict__ W2, const float* __restrict__ b2,
    const float* __restrict__ W3, const float* __restrict__ b3,
    const float* __restrict__ W4, const float* __restrict__ b4,
    const float* __restrict__ alpha,
    const float* __restrict__ ws,
    float* __restrict__ fp)
{
    const int tid = threadIdx.x;
    const int k   = blockIdx.y;
    const int g   = blockIdx.z;
    const int b   = (blockIdx.x * 256 + tid) * VB;
    const int l0  = g * LG;

    float acc[VB] = {0.f, 0.f, 0.f, 0.f};

    for (int j = 0; j < LG; ++j) {
        const int l  = l0 + j;
        const int kl = k * LL + l;
        const float scale = ws[WS_SCALE + l];
        const float shift = ws[WS_SHIFT + l];

        const float4 xv = *(const float4*)&xT[l * BATCH + b];
        float xn[VB] = {
            fmaf(xv.x, scale, shift), fmaf(xv.y, scale, shift),
            fmaf(xv.z, scale, shift), fmaf(xv.w, scale, shift)
        };

        // layer 1: 1 -> 8
        const float* w1  = W1 + kl * 8;
        const float* bb1 = b1 + kl * 8;
        float h1[VB][8];
        #pragma unroll
        for (int h = 0; h < 8; ++h) {
            const float w = w1[h], bb = bb1[h];
            #pragma unroll
            for (int v = 0; v < VB; ++v)
                h1[v][h] = fmaxf(fmaf(xn[v], w, bb), 0.f);
        }

        // layer 2: 8 -> 8
        const float* w2  = W2 + kl * 64;
        const float* bb2 = b2 + kl * 8;
        float h2[VB][8];
        #pragma unroll
        for (int i = 0; i < 8; ++i) {
            const float bb = bb2[i];
            float t[VB] = {bb, bb, bb, bb};
            #pragma unroll
            for (int h = 0; h < 8; ++h) {
                const float w = w2[i * 8 + h];
                #pragma unroll
                for (int v = 0; v < VB; ++v)
                    t[v] = fmaf(h1[v][h], w, t[v]);
            }
            #pragma unroll
            for (int v = 0; v < VB; ++v)
                h2[v][i] = fmaxf(t[v], 0.f);
        }

        // layer 3: 8 -> 6
        const float* w3  = W3 + kl * 48;
        const float* bb3 = b3 + kl * 6;
        float h3[VB][6];
        #pragma unroll
        for (int jj = 0; jj < 6; ++jj) {
            const float bb = bb3[jj];
            float t[VB] = {bb, bb, bb, bb};
            #pragma unroll
            for (int i = 0; i < 8; ++i) {
                const float w = w3[jj * 8 + i];
                #pragma unroll
                for (int v = 0; v < VB; ++v)
                    t[v] = fmaf(h2[v][i], w, t[v]);
            }
            #pragma unroll
            for (int v = 0; v < VB; ++v)
                h3[v][jj] = fmaxf(t[v], 0.f);
        }

        // layer 4: 6 -> 1, then alpha-weighted accumulate
        const float* w4 = W4 + kl * 6;
        const float b4v = b4[kl];
        const float a   = alpha[l * KK + k];
        #pragma unroll
        for (int v = 0; v < VB; ++v) {
            float f = b4v;
            #pragma unroll
            for (int jj = 0; jj < 6; ++jj)
                f = fmaf(h3[v][jj], w4[jj], f);
            acc[v] = fmaf(a, f, acc[v]);
        }
    }

    float4 o = {acc[0], acc[1], acc[2], acc[3]};
    *(float4*)&fp[(g * KK + k) * BATCH + b] = o;
}

// ---------------------------------------------------------------------------
// reduce: out[b][k] = beta[k] + sum_g fp[g][k][b]; coalesced loads.
// ---------------------------------------------------------------------------
__global__ __launch_bounds__(256) void reduce_kernel(
    const float* __restrict__ fp,
    const float* __restrict__ beta,
    float* __restrict__ out)
{
    const int tid = threadIdx.x;
    const int k   = blockIdx.y;
    const int b   = blockIdx.x * 256 + tid;

    float acc = beta[k];
    #pragma unroll
    for (int g = 0; g < NLG; ++g)
        acc += fp[(g * KK + k) * BATCH + b];
    out[(size_t)b * KK + k] = acc;
}

// ---------------------------------------------------------------------------
// fallbacks (small workspace) — unchanged from R4, proven correct.
// ---------------------------------------------------------------------------
__device__ __forceinline__ float mlp_eval(
    float xn, int kl,
    const float* __restrict__ W1, const float* __restrict__ b1,
    const float* __restrict__ W2, const float* __restrict__ b2,
    const float* __restrict__ W3, const float* __restrict__ b3,
    const float* __restrict__ W4, const float* __restrict__ b4)
{
    const float* w1  = W1 + kl * 8;
    const float* bb1 = b1 + kl * 8;
    float h1[8];
    #pragma unroll
    for (int h = 0; h < 8; ++h)
        h1[h] = fmaxf(fmaf(xn, w1[h], bb1[h]), 0.f);

    const float* w2  = W2 + kl * 64;
    const float* bb2 = b2 + kl * 8;
    float h2[8];
    #pragma unroll
    for (int i = 0; i < 8; ++i) {
        float t = bb2[i];
        #pragma unroll
        for (int h = 0; h < 8; ++h)
            t = fmaf(h1[h], w2[i * 8 + h], t);
        h2[i] = fmaxf(t, 0.f);
    }

    const float* w3  = W3 + kl * 48;
    const float* bb3 = b3 + kl * 6;
    float h3[6];
    #pragma unroll
    for (int j = 0; j < 6; ++j) {
        float t = bb3[j];
        #pragma unroll
        for (int i = 0; i < 8; ++i)
            t = fmaf(h2[i], w3[j * 8 + i], t);
        h3[j] = fmaxf(t, 0.f);
    }

    const float* w4 = W4 + kl * 6;
    float f = b4[kl];
    #pragma unroll
    for (int j = 0; j < 6; ++j)
        f = fmaf(h3[j], w4[j], f);
    return f;
}

__global__ __launch_bounds__(256) void stats_small_kernel(
    const float* __restrict__ x,
    const float* __restrict__ gamma,
    const float* __restrict__ bn_bias,
    float* __restrict__ ws)
{
    const int l   = blockIdx.x;
    const int tid = threadIdx.x;

    float s = 0.f, s2 = 0.f;
    for (int b = tid; b < BATCH; b += 256) {
        float v = x[b * LL + l];
        s  += v;
        s2  = fmaf(v, v, s2);
    }
    for (int off = 32; off > 0; off >>= 1) {
        s  += __shfl_down(s,  off);
        s2 += __shfl_down(s2, off);
    }
    __shared__ float red[8];
    const int wave = tid >> 6;
    if ((tid & 63) == 0) { red[wave] = s; red[4 + wave] = s2; }
    __syncthreads();
    if (tid == 0) {
        s  = red[0] + red[1] + red[2] + red[3];
        s2 = red[4] + red[5] + red[6] + red[7];
        const float inv_b = 1.f / (float)BATCH;
        float mean = s * inv_b;
        float var  = fmaf(s2, inv_b, -mean * mean);
        float scale = rsqrtf(var + BN_EPS) * gamma[l];
        ws[WS_SCALE + l] = scale;
        ws[WS_SHIFT + l] = fmaf(-mean, scale, bn_bias[l]);
    }
}

__global__ __launch_bounds__(256) void mlp_lds_direct_kernel(
    const float* __restrict__ x,
    const float* __restrict__ W1, const float* __restrict__ b1,
    const float* __restrict__ W2, const float* __restrict__ b2,
    const float* __restrict__ W3, const float* __restrict__ b3,
    const float* __restrict__ W4, const float* __restrict__ b4,
    const float* __restrict__ alpha, const float* __restrict__ beta,
    const float* __restrict__ ws,
    float* __restrict__ out)
{
    __shared__ float xs[256 * LL];
    const int tid = threadIdx.x;
    const int k   = blockIdx.y;
    const int b0  = blockIdx.x * 256;

    const float* xsrc = x + (size_t)b0 * LL;
    #pragma unroll
    for (int i = 0; i < LL; ++i)
        xs[i * 256 + tid] = xsrc[i * 256 + tid];
    __syncthreads();

    float acc = beta[k];
    for (int l = 0; l < LL; ++l) {
        const int kl = k * LL + l;
        const float xn = fmaf(xs[tid * LL + l], ws[WS_SCALE + l], ws[WS_SHIFT + l]);
        const float f  = mlp_eval(xn, kl, W1, b1, W2, b2, W3, b3, W4, b4);
        acc = fmaf(alpha[l * KK + k], f, acc);
    }
    out[(size_t)(b0 + tid) * KK + k] = acc;
}

extern "C" void kernel_launch(void* const* d_in, const int* in_sizes, int n_in,
                              void* d_out, int out_size, void* d_ws, size_t ws_size,
                              hipStream_t stream) {
    const float* x       = (const float*)d_in[0];
    const float* gamma   = (const float*)d_in[1];
    const float* bn_bias = (const float*)d_in[2];
    const float* W1      = (const float*)d_in[3];
    const float* b1      = (const float*)d_in[4];
    const float* W2      = (const float*)d_in[5];
    const float* b2      = (const float*)d_in[6];
    const float* W3      = (const float*)d_in[7];
    const float* b3      = (const float*)d_in[8];
    const float* W4      = (const float*)d_in[9];
    const float* b4      = (const float*)d_in[10];
    const float* alpha   = (const float*)d_in[11];
    const float* beta    = (const float*)d_in[12];

    float* out = (float*)d_out;
    float* ws  = (float*)d_ws;
    float* xT  = ws + WS_XT;
    float* fp  = ws + WS_FP;

    const bool fast = ws_size >= (size_t)WS_END * sizeof(float);

    if (fast) {
        prep_kernel<<<dim3(PREPB), dim3(256), 0, stream>>>(x, xT, ws + WS_PART);
        stats2_kernel<<<dim3(1), dim3(64), 0, stream>>>(ws + WS_PART, gamma, bn_bias, ws);
        eval_kernel<<<dim3(BATCH / (256 * VB), KK, NLG), dim3(256), 0, stream>>>(
            xT, W1, b1, W2, b2, W3, b3, W4, b4, alpha, ws, fp);
        reduce_kernel<<<dim3(BATCH / 256, KK), dim3(256), 0, stream>>>(fp, beta, out);
    } else {
        stats_small_kernel<<<dim3(LL), dim3(256), 0, stream>>>(x, gamma, bn_bias, ws);
        mlp_lds_direct_kernel<<<dim3(BATCH / 256, KK), dim3(256), 0, stream>>>(
            x, W1, b1, W2, b2, W3, b3, W4, b4, alpha, beta, ws, out);
    }
}

// Round 6
// 102.211 us; speedup vs baseline: 1.5151x; 1.1079x over previous
//
#include <hip/hip_runtime.h>

// Problem constants (match reference)
#define BATCH  8192
#define KK     25
#define LL     25
#define BN_EPS 1e-5f
#define PREPB  32              // prep blocks = BATCH/256
#define LG     5               // l-values per eval block
#define NLG    (LL / LG)
#define VB     4               // batch elements per thread in eval (reg blocking)
#define WSTRIDE 160            // per-l LDS weight-slab stride (floats)

// Workspace layout (float offsets):
#define WS_PART   0                         // [PREPB][50] partial sums
#define WS_SCALE  1600                      // (fallback path only)
#define WS_SHIFT  1632
#define WS_XT     2048                      // [LL][BATCH] transposed x
#define WS_FP     (WS_XT + LL * BATCH)      // [NLG][KK][BATCH] partial outputs
#define WS_END    (WS_FP + NLG * KK * BATCH)

// ---------------------------------------------------------------------------
// prep: coalesced read of x chunk -> LDS; coalesced transposed write to xT;
// per-column partial sum/sumsq (no atomics). 32 blocks x 256 rows.
// ---------------------------------------------------------------------------
__global__ __launch_bounds__(256) void prep_kernel(
    const float* __restrict__ x,
    float* __restrict__ xT,
    float* __restrict__ part)
{
    __shared__ float xs[256 * LL];          // 25.6 KB
    const int tid = threadIdx.x;
    const int b0  = blockIdx.x * 256;

    const float* src = x + (size_t)b0 * LL;
    #pragma unroll
    for (int i = 0; i < LL; ++i)
        xs[i * 256 + tid] = src[i * 256 + tid];
    __syncthreads();

    // transposed write: lanes write consecutive b -> coalesced.
    // LDS read stride 25 dwords, gcd(25,32)=1 -> 2 lanes/bank (free).
    #pragma unroll
    for (int l = 0; l < LL; ++l)
        xT[l * BATCH + b0 + tid] = xs[tid * LL + l];

    float s = 0.f, s2 = 0.f;
    if (tid < 200) {
        const int l = tid % LL;
        const int g = tid / LL;
        #pragma unroll
        for (int r = 0; r < 32; ++r) {
            const float v = xs[(g * 32 + r) * LL + l];
            s += v;
            s2 = fmaf(v, v, s2);
        }
    }
    __syncthreads();
    if (tid < 200) { xs[tid] = s; xs[200 + tid] = s2; }
    __syncthreads();

    if (tid < 50) {
        const int c = tid;
        float t = 0.f;
        if (c < LL) {
            #pragma unroll
            for (int g = 0; g < 8; ++g) t += xs[g * LL + c];
        } else {
            #pragma unroll
            for (int g = 0; g < 8; ++g) t += xs[200 + g * LL + (c - LL)];
        }
        part[blockIdx.x * 50 + c] = t;
    }
}

// ---------------------------------------------------------------------------
// eval: block (bchunk, k, g). R6 redesign:
//  - ALL weights for this block's 5 (k,l) nets staged into LDS once
//    (3.2 KB, coalesced) -> compute reads are wave-uniform ds_read
//    broadcasts, freeing the ~102-SGPR ceiling that forced just-in-time
//    s_load reloads (the R3-R5 VALUBusy~31-50% stall).
//  - stats2 folded into the preamble: 10 threads re-reduce the 32 prep
//    partials for this block's columns (one fewer launch).
//  - j-loop fully unrolled so ds_reads software-pipeline across layers.
// Thread handles VB=4 batch elems: float4 xT load, float4 fp store.
// LDS weight slab layout per j (stride WSTRIDE=160):
//   [0:8) w1  [8:16) b1  [16:80) w2  [80:88) b2  [88:136) w3
//   [136:142) b3  [142:148) w4  [148] b4  [149] alpha  [150] scale  [151] shift
// ---------------------------------------------------------------------------
__global__ __launch_bounds__(256, 3) void eval_kernel(
    const float* __restrict__ xT,
    const float* __restrict__ W1, const float* __restrict__ b1,
    const float* __restrict__ W2, const float* __restrict__ b2,
    const float* __restrict__ W3, const float* __restrict__ b3,
    const float* __restrict__ W4, const float* __restrict__ b4,
    const float* __restrict__ alpha,
    const float* __restrict__ part,
    const float* __restrict__ gamma,
    const float* __restrict__ bn_bias,
    float* __restrict__ fp)
{
    __shared__ float wl[LG * WSTRIDE];      // 800 floats = 3.2 KB
    __shared__ float tmp[2 * LG];

    const int tid = threadIdx.x;
    const int k   = blockIdx.y;
    const int g   = blockIdx.z;
    const int l0  = g * LG;
    const int kl0 = k * LL + l0;
    const int b   = (blockIdx.x * 256 + tid) * VB;

    // ---- stage weights (coalesced-ish, once per block) ----
    if (tid < 40) {
        const int j = tid >> 3, e = tid & 7;
        wl[j * WSTRIDE +      e] = W1[(kl0 + j) * 8 + e];
        wl[j * WSTRIDE +  8 + e] = b1[(kl0 + j) * 8 + e];
        wl[j * WSTRIDE + 80 + e] = b2[(kl0 + j) * 8 + e];
    }
    {   // W2: 5*64 = 320 elements
        int t = tid;
        const int j = t >> 6, e = t & 63;
        wl[j * WSTRIDE + 16 + e] = W2[(kl0 + j) * 64 + e];
        t += 256;
        if (t < LG * 64) {
            const int j2 = t >> 6, e2 = t & 63;
            wl[j2 * WSTRIDE + 16 + e2] = W2[(kl0 + j2) * 64 + e2];
        }
    }
    if (tid < 240) {                         // W3: 5*48
        const int j = tid / 48, e = tid % 48;
        wl[j * WSTRIDE + 88 + e] = W3[(kl0 + j) * 48 + e];
    }
    if (tid < 30) {                          // b3, w4: 5*6 each
        const int j = tid / 6, e = tid % 6;
        wl[j * WSTRIDE + 136 + e] = b3[(kl0 + j) * 6 + e];
        wl[j * WSTRIDE + 142 + e] = W4[(kl0 + j) * 6 + e];
    }
    if (tid < LG) {
        wl[tid * WSTRIDE + 148] = b4[kl0 + tid];
        wl[tid * WSTRIDE + 149] = alpha[(l0 + tid) * KK + k];
    }

    // ---- stats preamble: reduce prep partials for this block's columns ----
    if (tid >= 128 && tid < 128 + 2 * LG) {
        const int t2  = tid - 128;                      // 0..9
        const int col = (t2 < LG) ? (l0 + t2) : (LL + l0 + t2 - LG);
        float s = 0.f;
        #pragma unroll
        for (int i = 0; i < PREPB; ++i)
            s += part[i * 50 + col];
        tmp[t2] = s;
    }
    __syncthreads();
    if (tid < LG) {
        const float s = tmp[tid], s2 = tmp[LG + tid];
        const float inv_b = 1.f / (float)BATCH;
        const float mean  = s * inv_b;
        const float var   = fmaf(s2, inv_b, -mean * mean);
        const float scale = rsqrtf(var + BN_EPS) * gamma[l0 + tid];
        wl[tid * WSTRIDE + 150] = scale;
        wl[tid * WSTRIDE + 151] = fmaf(-mean, scale, bn_bias[l0 + tid]);
    }
    __syncthreads();

    // ---- compute ----
    float acc[VB] = {0.f, 0.f, 0.f, 0.f};

    #pragma unroll
    for (int j = 0; j < LG; ++j) {
        const float* w = wl + j * WSTRIDE;
        const float scale = w[150];
        const float shift = w[151];

        const float4 xv = *(const float4*)&xT[(l0 + j) * BATCH + b];
        float xn[VB] = {
            fmaf(xv.x, scale, shift), fmaf(xv.y, scale, shift),
            fmaf(xv.z, scale, shift), fmaf(xv.w, scale, shift)
        };

        // layer 1: 1 -> 8
        float h1[VB][8];
        #pragma unroll
        for (int h = 0; h < 8; ++h) {
            const float ww = w[h], bb = w[8 + h];
            #pragma unroll
            for (int v = 0; v < VB; ++v)
                h1[v][h] = fmaxf(fmaf(xn[v], ww, bb), 0.f);
        }

        // layer 2: 8 -> 8
        float h2[VB][8];
        #pragma unroll
        for (int i = 0; i < 8; ++i) {
            const float bb = w[80 + i];
            float t[VB] = {bb, bb, bb, bb};
            #pragma unroll
            for (int h = 0; h < 8; ++h) {
                const float ww = w[16 + i * 8 + h];
                #pragma unroll
                for (int v = 0; v < VB; ++v)
                    t[v] = fmaf(h1[v][h], ww, t[v]);
            }
            #pragma unroll
            for (int v = 0; v < VB; ++v)
                h2[v][i] = fmaxf(t[v], 0.f);
        }

        // layer 3: 8 -> 6
        float h3[VB][6];
        #pragma unroll
        for (int jj = 0; jj < 6; ++jj) {
            const float bb = w[136 + jj];
            float t[VB] = {bb, bb, bb, bb};
            #pragma unroll
            for (int i = 0; i < 8; ++i) {
                const float ww = w[88 + jj * 8 + i];
                #pragma unroll
                for (int v = 0; v < VB; ++v)
                    t[v] = fmaf(h2[v][i], ww, t[v]);
            }
            #pragma unroll
            for (int v = 0; v < VB; ++v)
                h3[v][jj] = fmaxf(t[v], 0.f);
        }

        // layer 4: 6 -> 1, alpha-weighted accumulate
        const float b4v = w[148];
        const float a   = w[149];
        #pragma unroll
        for (int v = 0; v < VB; ++v) {
            float f = b4v;
            #pragma unroll
            for (int jj = 0; jj < 6; ++jj)
                f = fmaf(h3[v][jj], w[142 + jj], f);
            acc[v] = fmaf(a, f, acc[v]);
        }
    }

    float4 o = {acc[0], acc[1], acc[2], acc[3]};
    *(float4*)&fp[(g * KK + k) * BATCH + b] = o;
}

// ---------------------------------------------------------------------------
// reduce: out[b][k] = beta[k] + sum_g fp[g][k][b]; coalesced loads.
// ---------------------------------------------------------------------------
__global__ __launch_bounds__(256) void reduce_kernel(
    const float* __restrict__ fp,
    const float* __restrict__ beta,
    float* __restrict__ out)
{
    const int tid = threadIdx.x;
    const int k   = blockIdx.y;
    const int b   = blockIdx.x * 256 + tid;

    float acc = beta[k];
    #pragma unroll
    for (int g = 0; g < NLG; ++g)
        acc += fp[(g * KK + k) * BATCH + b];
    out[(size_t)b * KK + k] = acc;
}

// ---------------------------------------------------------------------------
// fallbacks (small workspace) — unchanged, proven correct.
// ---------------------------------------------------------------------------
__device__ __forceinline__ float mlp_eval(
    float xn, int kl,
    const float* __restrict__ W1, const float* __restrict__ b1,
    const float* __restrict__ W2, const float* __restrict__ b2,
    const float* __restrict__ W3, const float* __restrict__ b3,
    const float* __restrict__ W4, const float* __restrict__ b4)
{
    const float* w1  = W1 + kl * 8;
    const float* bb1 = b1 + kl * 8;
    float h1[8];
    #pragma unroll
    for (int h = 0; h < 8; ++h)
        h1[h] = fmaxf(fmaf(xn, w1[h], bb1[h]), 0.f);

    const float* w2  = W2 + kl * 64;
    const float* bb2 = b2 + kl * 8;
    float h2[8];
    #pragma unroll
    for (int i = 0; i < 8; ++i) {
        float t = bb2[i];
        #pragma unroll
        for (int h = 0; h < 8; ++h)
            t = fmaf(h1[h], w2[i * 8 + h], t);
        h2[i] = fmaxf(t, 0.f);
    }

    const float* w3  = W3 + kl * 48;
    const float* bb3 = b3 + kl * 6;
    float h3[6];
    #pragma unroll
    for (int j = 0; j < 6; ++j) {
        float t = bb3[j];
        #pragma unroll
        for (int i = 0; i < 8; ++i)
            t = fmaf(h2[i], w3[j * 8 + i], t);
        h3[j] = fmaxf(t, 0.f);
    }

    const float* w4 = W4 + kl * 6;
    float f = b4[kl];
    #pragma unroll
    for (int j = 0; j < 6; ++j)
        f = fmaf(h3[j], w4[j], f);
    return f;
}

__global__ __launch_bounds__(256) void stats_small_kernel(
    const float* __restrict__ x,
    const float* __restrict__ gamma,
    const float* __restrict__ bn_bias,
    float* __restrict__ ws)
{
    const int l   = blockIdx.x;
    const int tid = threadIdx.x;

    float s = 0.f, s2 = 0.f;
    for (int b = tid; b < BATCH; b += 256) {
        float v = x[b * LL + l];
        s  += v;
        s2  = fmaf(v, v, s2);
    }
    for (int off = 32; off > 0; off >>= 1) {
        s  += __shfl_down(s,  off);
        s2 += __shfl_down(s2, off);
    }
    __shared__ float red[8];
    const int wave = tid >> 6;
    if ((tid & 63) == 0) { red[wave] = s; red[4 + wave] = s2; }
    __syncthreads();
    if (tid == 0) {
        s  = red[0] + red[1] + red[2] + red[3];
        s2 = red[4] + red[5] + red[6] + red[7];
        const float inv_b = 1.f / (float)BATCH;
        float mean = s * inv_b;
        float var  = fmaf(s2, inv_b, -mean * mean);
        float scale = rsqrtf(var + BN_EPS) * gamma[l];
        ws[WS_SCALE + l] = scale;
        ws[WS_SHIFT + l] = fmaf(-mean, scale, bn_bias[l]);
    }
}

__global__ __launch_bounds__(256) void mlp_lds_direct_kernel(
    const float* __restrict__ x,
    const float* __restrict__ W1, const float* __restrict__ b1,
    const float* __restrict__ W2, const float* __restrict__ b2,
    const float* __restrict__ W3, const float* __restrict__ b3,
    const float* __restrict__ W4, const float* __restrict__ b4,
    const float* __restrict__ alpha, const float* __restrict__ beta,
    const float* __restrict__ ws,
    float* __restrict__ out)
{
    __shared__ float xs[256 * LL];
    const int tid = threadIdx.x;
    const int k   = blockIdx.y;
    const int b0  = blockIdx.x * 256;

    const float* xsrc = x + (size_t)b0 * LL;
    #pragma unroll
    for (int i = 0; i < LL; ++i)
        xs[i * 256 + tid] = xsrc[i * 256 + tid];
    __syncthreads();

    float acc = beta[k];
    for (int l = 0; l < LL; ++l) {
        const int kl = k * LL + l;
        const float xn = fmaf(xs[tid * LL + l], ws[WS_SCALE + l], ws[WS_SHIFT + l]);
        const float f  = mlp_eval(xn, kl, W1, b1, W2, b2, W3, b3, W4, b4);
        acc = fmaf(alpha[l * KK + k], f, acc);
    }
    out[(size_t)(b0 + tid) * KK + k] = acc;
}

extern "C" void kernel_launch(void* const* d_in, const int* in_sizes, int n_in,
                              void* d_out, int out_size, void* d_ws, size_t ws_size,
                              hipStream_t stream) {
    const float* x       = (const float*)d_in[0];
    const float* gamma   = (const float*)d_in[1];
    const float* bn_bias = (const float*)d_in[2];
    const float* W1      = (const float*)d_in[3];
    const float* b1      = (const float*)d_in[4];
    const float* W2      = (const float*)d_in[5];
    const float* b2      = (const float*)d_in[6];
    const float* W3      = (const float*)d_in[7];
    const float* b3      = (const float*)d_in[8];
    const float* W4      = (const float*)d_in[9];
    const float* b4      = (const float*)d_in[10];
    const float* alpha   = (const float*)d_in[11];
    const float* beta    = (const float*)d_in[12];

    float* out = (float*)d_out;
    float* ws  = (float*)d_ws;
    float* xT  = ws + WS_XT;
    float* fp  = ws + WS_FP;

    const bool fast = ws_size >= (size_t)WS_END * sizeof(float);

    if (fast) {
        prep_kernel<<<dim3(PREPB), dim3(256), 0, stream>>>(x, xT, ws + WS_PART);
        eval_kernel<<<dim3(BATCH / (256 * VB), KK, NLG), dim3(256), 0, stream>>>(
            xT, W1, b1, W2, b2, W3, b3, W4, b4, alpha,
            ws + WS_PART, gamma, bn_bias, fp);
        reduce_kernel<<<dim3(BATCH / 256, KK), dim3(256), 0, stream>>>(fp, beta, out);
    } else {
        stats_small_kernel<<<dim3(LL), dim3(256), 0, stream>>>(x, gamma, bn_bias, ws);
        mlp_lds_direct_kernel<<<dim3(BATCH / 256, KK), dim3(256), 0, stream>>>(
            x, W1, b1, W2, b2, W3, b3, W4, b4, alpha, beta, ws, out);
    }
}